// Round 2
// baseline (662.257 us; speedup 1.0000x reference)
//
#include <hip/hip_runtime.h>

#define T_ 512
#define K_ 128
#define B_ 256

// One block per batch, 1024 threads = 16 waves.
// Waves 0-7:  forward (factored logsumexp), j = lin>>2, c = lin&3 -> i in [c*32, c*32+32)
// Waves 8-15: viterbi (max/argmax), same mapping.
// Per-thread transition slice = 32 floats in REGISTERS (round-1 failure: 64-float
// table at launch_bounds(512,2) was demoted to scratch -> VGPR_Count 56, 5x slowdown).
// alpha/viterbi vectors double-buffered in LDS, one barrier per step.
// Backpointers in LDS (uint8, 64 KB), never touch HBM.
__global__ __launch_bounds__(1024, 4) void crf_main(
    const float* __restrict__ emissions,
    const int* __restrict__ tag_ids,
    const int* __restrict__ lengths,
    const float* __restrict__ transitions,
    float* __restrict__ out,
    float* __restrict__ ws_ll,
    int* __restrict__ ws_cnt)
{
    __shared__ unsigned char bpLDS[T_ * K_];            // 64 KB backpointers
    __shared__ __align__(16) float eaBuf[2][K_];        // exp(alpha - S), double buffered
    __shared__ __align__(16) float vaBuf[2][K_];        // viterbi scores, double buffered
    __shared__ __align__(16) float wmax[2][8];          // per-fwd-wave max of alpha
    __shared__ float redLDS[8];                         // score partials (live through loop)
    __shared__ int   redILDS[8];                        // accuracy-count partials
    __shared__ unsigned char decLDS[T_];                // decoded chain
    __shared__ int ltagLDS;

    const int b   = blockIdx.x;
    const int tid = threadIdx.x;
    const int len = lengths[b];
    const float* emB = emissions + (size_t)b * T_ * K_;
    const int*  tagB = tag_ids + b * T_;

    // ---------------- sequence score (unary + binary), one t per thread ----------------
    if (tid < T_) {
        int t = tid;
        float s = 0.f;
        if (t < len) {
            int tg = tagB[t];
            s = emB[t * K_ + tg];
            if (t >= 1) s += transitions[tagB[t - 1] * K_ + tg];
        }
        #pragma unroll
        for (int m = 1; m < 64; m <<= 1) s += __shfl_xor(s, m);
        if ((tid & 63) == 0) redLDS[tid >> 6] = s;
    }

    const int role = tid >> 9;          // 0 = forward, 1 = viterbi
    const int lin  = tid & 511;
    const int j = lin >> 2;             // column 0..127
    const int c = lin & 3;              // quarter of the i-range
    const int wv = tid >> 6;            // wave id 0..15

    // ---------------- per-thread transition slice (32 registers) ----------------
    float tbl[32];
    if (role == 0) {
        #pragma unroll
        for (int k = 0; k < 32; ++k)
            tbl[k] = __expf(transitions[(c * 32 + k) * K_ + j]);
    } else {
        #pragma unroll
        for (int k = 0; k < 32; ++k)
            tbl[k] = transitions[(c * 32 + k) * K_ + j];
    }

    // ---------------- init t = 0 ----------------
    float e0 = emB[j];
    if (role == 0) {
        if (c == 0) eaBuf[0][j] = __expf(e0);           // offset S0 = 0
        float wm = e0;
        #pragma unroll
        for (int m = 1; m < 64; m <<= 1) wm = fmaxf(wm, __shfl_xor(wm, m));
        if ((lin & 63) == 0) wmax[0][wv] = wm;          // wv = 0..7 for fwd waves
    } else {
        if (c == 0) vaBuf[0][j] = e0;
    }
    __syncthreads();

    // ---------------- main recurrence ----------------
    int cur = 0;
    float Sprev = 0.f;                                  // offset of current ea buffer
    for (int t = 1; t < len; ++t) {
        const float* em = emB + t * K_;
        if (role == 0) {
            float4 w0 = *(const float4*)&wmax[cur][0];
            float4 w1 = *(const float4*)&wmax[cur][4];
            float Scur = fmaxf(fmaxf(fmaxf(w0.x, w0.y), fmaxf(w0.z, w0.w)),
                               fmaxf(fmaxf(w1.x, w1.y), fmaxf(w1.z, w1.w)));
            float emit = em[j];
            const float* ea = &eaBuf[cur][c * 32];
            float a0 = 0.f, a1 = 0.f, a2 = 0.f, a3 = 0.f;
            #pragma unroll
            for (int k = 0; k < 8; ++k) {
                float4 e4 = *(const float4*)(ea + 4 * k);
                a0 = fmaf(e4.x, tbl[4 * k + 0], a0);
                a1 = fmaf(e4.y, tbl[4 * k + 1], a1);
                a2 = fmaf(e4.z, tbl[4 * k + 2], a2);
                a3 = fmaf(e4.w, tbl[4 * k + 3], a3);
            }
            float dot = (a0 + a1) + (a2 + a3);
            dot += __shfl_xor(dot, 1);                  // combine the four i-quarters
            dot += __shfl_xor(dot, 2);
            float anew = __logf(dot) + Sprev + emit;
            if (c == 0) eaBuf[cur ^ 1][j] = __expf(anew - Scur);
            float wm = anew;
            #pragma unroll
            for (int m = 1; m < 64; m <<= 1) wm = fmaxf(wm, __shfl_xor(wm, m));
            if ((lin & 63) == 0) wmax[cur ^ 1][wv] = wm;
            Sprev = Scur;
        } else {
            float emit = em[j];
            const float* va = &vaBuf[cur][c * 32];
            float mB = -3.4028235e38f;
            int arg = 0;
            #pragma unroll
            for (int k = 0; k < 8; ++k) {               // ascending i, strict > = first-max-wins
                float4 v4 = *(const float4*)(va + 4 * k);
                float s0 = v4.x + tbl[4 * k + 0]; if (s0 > mB) { mB = s0; arg = 4 * k + 0; }
                float s1 = v4.y + tbl[4 * k + 1]; if (s1 > mB) { mB = s1; arg = 4 * k + 1; }
                float s2 = v4.z + tbl[4 * k + 2]; if (s2 > mB) { mB = s2; arg = 4 * k + 2; }
                float s3 = v4.w + tbl[4 * k + 3]; if (s3 > mB) { mB = s3; arg = 4 * k + 3; }
            }
            arg += c * 32;
            #pragma unroll
            for (int d = 1; d < 4; d <<= 1) {           // quad lexicographic (max val, min idx)
                float om = __shfl_xor(mB, d);
                int   oa = __shfl_xor(arg, d);
                if (om > mB || (om == mB && oa < arg)) { mB = om; arg = oa; }
            }
            if (c == 0) {
                vaBuf[cur ^ 1][j] = mB + emit;
                bpLDS[t * K_ + j] = (unsigned char)arg;
            }
        }
        cur ^= 1;
        __syncthreads();
    }

    // ---------------- logZ (forward wave 0; Sprev valid there) ----------------
    float logZv = 0.f;
    if (tid < 64) {
        float s = eaBuf[cur][tid] + eaBuf[cur][tid + 64];
        #pragma unroll
        for (int m = 1; m < 64; m <<= 1) s += __shfl_xor(s, m);
        logZv = Sprev + __logf(s);                      // valid in lane 0 (tid 0)
    }

    // ---------------- last tag: argmax_j v_final (first-max-wins) ----------------
    if (tid >= 512 && tid < 576) {
        int l = tid - 512;
        float m = vaBuf[cur][l]; int a = l;
        float v2 = vaBuf[cur][l + 64];
        if (v2 > m) { m = v2; a = l + 64; }
        #pragma unroll
        for (int sft = 1; sft < 64; sft <<= 1) {
            float om = __shfl_xor(m, sft);
            int   oa = __shfl_xor(a, sft);
            if (om > m || (om == m && oa < a)) { m = om; a = oa; }
        }
        if (l == 0) ltagLDS = a;
    }
    __syncthreads();

    // ---------------- backtrace (serial chain through LDS) ----------------
    if (tid == 0) {
        int tg = ltagLDS;
        for (int t = T_ - 1; t >= 1; --t) {
            decLDS[t] = (unsigned char)tg;
            if (t < len) tg = bpLDS[t * K_ + tg];       // identity bp for t >= len
        }
        decLDS[0] = (unsigned char)tg;
    }
    __syncthreads();

    // ---------------- decoded write + accuracy count ----------------
    if (tid < T_) {
        int t = tid;
        int dv = decLDS[t];
        out[1 + b * T_ + t] = (float)dv;
        int good = (t < len && tagB[t] == dv) ? 1 : 0;
        #pragma unroll
        for (int m = 1; m < 64; m <<= 1) good += __shfl_xor(good, m);
        if ((tid & 63) == 0) redILDS[tid >> 6] = good;
    }
    __syncthreads();

    if (tid == 0) {
        float sc = 0.f; int cnt = 0;
        #pragma unroll
        for (int w = 0; w < 8; ++w) { sc += redLDS[w]; cnt += redILDS[w]; }
        ws_ll[b]  = sc - logZv;                         // log-likelihood of batch b
        ws_cnt[b] = cnt;
    }
}

// Final reduction: loss = -mean(ll), accuracy = sum(correct)/sum(len)
__global__ void crf_final(const float* __restrict__ ws_ll,
                          const int* __restrict__ ws_cnt,
                          const int* __restrict__ lengths,
                          float* __restrict__ out)
{
    __shared__ float sll[4];
    __shared__ int scnt[4], slen[4];
    int tid = threadIdx.x;                              // blockDim == B_ == 256
    float ll = ws_ll[tid];
    int   cn = ws_cnt[tid];
    int   L  = lengths[tid];
    #pragma unroll
    for (int m = 1; m < 64; m <<= 1) {
        ll += __shfl_xor(ll, m);
        cn += __shfl_xor(cn, m);
        L  += __shfl_xor(L, m);
    }
    if ((tid & 63) == 0) { sll[tid >> 6] = ll; scnt[tid >> 6] = cn; slen[tid >> 6] = L; }
    __syncthreads();
    if (tid == 0) {
        float llS = sll[0] + sll[1] + sll[2] + sll[3];
        int   cS  = scnt[0] + scnt[1] + scnt[2] + scnt[3];
        int   LS  = slen[0] + slen[1] + slen[2] + slen[3];
        out[0] = -llS / (float)B_;
        out[1 + B_ * T_] = (float)cS / (float)LS;
    }
}

extern "C" void kernel_launch(void* const* d_in, const int* in_sizes, int n_in,
                              void* d_out, int out_size, void* d_ws, size_t ws_size,
                              hipStream_t stream) {
    const float* emissions   = (const float*)d_in[0];
    const int*   tag_ids     = (const int*)d_in[1];
    const int*   lengths     = (const int*)d_in[2];
    const float* transitions = (const float*)d_in[3];
    float* out = (float*)d_out;

    float* ws_ll  = (float*)d_ws;
    int*   ws_cnt = (int*)((char*)d_ws + B_ * sizeof(float));

    crf_main<<<B_, 1024, 0, stream>>>(emissions, tag_ids, lengths, transitions,
                                      out, ws_ll, ws_cnt);
    crf_final<<<1, B_, 0, stream>>>(ws_ll, ws_cnt, lengths, out);
}